// Round 16
// baseline (492.661 us; speedup 1.0000x reference)
//
#include <hip/hip_runtime.h>
#include <hip/hip_bf16.h>
#include <stdint.h>

#define DM   1024
#define NH   16
#define SS   2048
#define BB   2
#define MT   4096   // B*S

typedef __attribute__((ext_vector_type(8))) short short8;
typedef __attribute__((ext_vector_type(4))) float f32x4;

typedef __attribute__((address_space(1))) const unsigned int as1_uint;
typedef __attribute__((address_space(3))) unsigned int as3_uint;

__device__ __forceinline__ void async16(const void* g, void* l) {
  __builtin_amdgcn_global_load_lds((as1_uint*)g, (as3_uint*)l, 16, 0, 0);
}

#define WAITV(n) asm volatile("s_waitcnt vmcnt(" #n ")" ::: "memory")
#define BARRIER_SB() do { __builtin_amdgcn_s_barrier(); __builtin_amdgcn_sched_barrier(0); } while (0)
#define EXP2(x) __builtin_amdgcn_exp2f(x)
#define QSCALE 0.180336879f   // 0.125 * log2(e)

__device__ __forceinline__ unsigned short f2bf(float f) {
  union { float f; unsigned u; } c; c.f = f;
  unsigned r = c.u + 0x7fffu + ((c.u >> 16) & 1u);
  return (unsigned short)(r >> 16);
}

__device__ __forceinline__ unsigned cvt_pk_bf16(float lo, float hi) {
  unsigned r;
  asm("v_cvt_pk_bf16_f32 %0, %1, %2" : "=v"(r) : "v"(lo), "v"(hi));
  return r;
}

__device__ __forceinline__ float swz16(float x) {
  return __uint_as_float((unsigned)__builtin_amdgcn_ds_swizzle((int)__float_as_uint(x), 0x401F));
}

// 16-way max with v_max3-fusable triples
__device__ __forceinline__ float max16(const float* s) {
  float a = fmaxf(fmaxf(s[0], s[1]), s[2]);
  float b = fmaxf(fmaxf(s[3], s[4]), s[5]);
  float c = fmaxf(fmaxf(s[6], s[7]), s[8]);
  float d = fmaxf(fmaxf(s[9], s[10]), s[11]);
  float e = fmaxf(fmaxf(s[12], s[13]), s[14]);
  float ab = fmaxf(fmaxf(a, b), c);
  float de = fmaxf(fmaxf(d, e), s[15]);
  return fmaxf(ab, de);
}

__device__ __forceinline__ void xcd_swz(int& bx, int& by, int& bz) {
  int GX = gridDim.x, GY = gridDim.y;
  int nwg = GX * GY * gridDim.z;
  int old = blockIdx.x + GX * (blockIdx.y + GY * blockIdx.z);
  int f2 = (old & 7) * (nwg >> 3) + (old >> 3);
  bz = f2 / (GX * GY);
  int rem = f2 % (GX * GY);
  bx = rem / GY;
  by = rem % GY;
}

// ---------------- fp32 -> bf16 convert (x and enc in one launch) -------------
__global__ __launch_bounds__(256) void k_conv2(
    const float* __restrict__ a, const float* __restrict__ b,
    unsigned short* __restrict__ oa, unsigned short* __restrict__ ob) {
  int bxr = blockIdx.x;
  const float* in = (bxr < 4096) ? a : b;
  unsigned short* out = (bxr < 4096) ? oa : ob;
  int i = ((bxr & 4095) * 256 + threadIdx.x) * 4;
  float4 v = *(const float4*)(in + i);
  uint2 u;
  u.x = (unsigned)f2bf(v.x) | ((unsigned)f2bf(v.y) << 16);
  u.y = (unsigned)f2bf(v.z) | ((unsigned)f2bf(v.w) << 16);
  *(uint2*)(out + i) = u;
}

// ---------------- fp32 [R][C] -> bf16 [C][R] transpose-convert ----------------
__global__ __launch_bounds__(256) void k_transpose_bf16(
    const float* __restrict__ in, unsigned short* __restrict__ out, int R, int C) {
  __shared__ float t[64][65];
  int c0 = blockIdx.x * 64, r0 = blockIdx.y * 64;
  int tx = threadIdx.x & 63, ty = threadIdx.x >> 6;  // 64 x 4
#pragma unroll
  for (int i = 0; i < 16; i++)
    t[ty + i * 4][tx] = in[(size_t)(r0 + ty + i * 4) * C + c0 + tx];
  __syncthreads();
#pragma unroll
  for (int i = 0; i < 16; i++)
    out[(size_t)(c0 + ty + i * 4) * R + r0 + tx] = f2bf(t[tx][ty + i * 4]);
}

struct PtrArr { const float* p[8]; };
__global__ __launch_bounds__(256) void k_transpose8(
    PtrArr ps, unsigned short* __restrict__ out0) {
  __shared__ float t[64][65];
  const float* in = ps.p[blockIdx.z];
  unsigned short* out = out0 + (size_t)blockIdx.z * 1048576;
  int c0 = blockIdx.x * 64, r0 = blockIdx.y * 64;
  int tx = threadIdx.x & 63, ty = threadIdx.x >> 6;
#pragma unroll
  for (int i = 0; i < 16; i++)
    t[ty + i * 4][tx] = in[(size_t)(r0 + ty + i * 4) * 1024 + c0 + tx];
  __syncthreads();
#pragma unroll
  for (int i = 0; i < 16; i++)
    out[(size_t)(c0 + ty + i * 4) * 1024 + r0 + tx] = f2bf(t[tx][ty + i * 4]);
}

// ---------------- 256x256 BK=64 8-wave phase-split GEMM core -----------------
__device__ __forceinline__ void stage_half(
    unsigned short* lds, int dst_off, const unsigned short* __restrict__ src,
    int sbase, int c0, int K, int kk, int tid) {
#pragma unroll
  for (int c = 0; c < 2; c++) {
    int e = ((c0 + c) * 512 + tid) * 8;
    int r_ = e >> 6, s_ = e & 63;
    async16(src + (size_t)(sbase + r_) * K + kk + (s_ ^ ((r_ & 4) << 2)),
            &lds[dst_off + e]);
  }
}

__device__ __forceinline__ void read_afrags(
    const unsigned short* lds, int aoff, int wm, int rh, int l15, int l4,
    short8 af[4][2]) {
#pragma unroll
  for (int i = 0; i < 4; i++) {
    int arow = wm * 128 + rh * 64 + i * 16 + l15;
#pragma unroll
    for (int ks = 0; ks < 2; ks++)
      af[i][ks] = *(const short8*)&lds[aoff + arow * 64 +
          ((ks * 32 + l4 * 8) ^ ((arow & 4) << 2))];
  }
}

__device__ __forceinline__ void read_bfrags(
    const unsigned short* lds, int boff, int wn, int ch, int l15, int l4,
    short8 bf[2][2]) {
#pragma unroll
  for (int j = 0; j < 2; j++) {
    int brw = wn * 64 + ch * 32 + j * 16 + l15;
#pragma unroll
    for (int ks = 0; ks < 2; ks++)
      bf[j][ks] = *(const short8*)&lds[boff + brw * 64 +
          ((ks * 32 + l4 * 8) ^ ((brw & 4) << 2))];
  }
}

#define MFMA_CL(RH, CH)                                                        \
  __builtin_amdgcn_s_barrier();                                                \
  asm volatile("s_waitcnt lgkmcnt(0)" ::: "memory");                           \
  __builtin_amdgcn_sched_barrier(0);                                           \
  __builtin_amdgcn_s_setprio(1);                                               \
  _Pragma("unroll")                                                            \
  for (int ks = 0; ks < 2; ks++)                                               \
    _Pragma("unroll")                                                          \
    for (int i = 0; i < 4; i++)                                                \
      _Pragma("unroll")                                                        \
      for (int j = 0; j < 2; j++)                                              \
        acc[(RH) * 4 + i][(CH) * 2 + j] =                                      \
            __builtin_amdgcn_mfma_f32_16x16x32_bf16(                           \
                af[i][ks], bf[j][ks], acc[(RH) * 4 + i][(CH) * 2 + j], 0, 0, 0); \
  __builtin_amdgcn_s_setprio(0);

#define GEMM256_LOOP(Asrc, Bsrc, ROWB, COLB)                                   \
  stage_half(lds, 32768, Bsrc, COLB, 0, K, kbeg, tid);                         \
  stage_half(lds, 32768, Bsrc, COLB, 2, K, kbeg, tid);                         \
  stage_half(lds, 0,     Asrc, ROWB, 0, K, kbeg, tid);                         \
  stage_half(lds, 0,     Asrc, ROWB, 2, K, kbeg, tid);                         \
  WAITV(0);                                                                    \
  __builtin_amdgcn_s_barrier();                                                \
  for (int t = 0; t < nk; t++) {                                               \
    int buf = t & 1, nb = buf ^ 1;                                             \
    int aoff = buf * 16384, boff = 32768 + buf * 16384;                        \
    int naoff = nb * 16384, nboff = 32768 + nb * 16384;                        \
    int kk2 = kbeg + (t + 1) * 64;                                             \
    bool more = (t + 1 < nk);                                                  \
    read_afrags(lds, aoff, wm, 0, l15, l4, af);                                \
    read_bfrags(lds, boff, wn, 0, l15, l4, bf);                                \
    if (more) {                                                                \
      stage_half(lds, nboff, Bsrc, COLB, 0, K, kk2, tid);                      \
      stage_half(lds, nboff, Bsrc, COLB, 2, K, kk2, tid);                      \
    }                                                                          \
    MFMA_CL(0, 0);                                                             \
    __builtin_amdgcn_s_barrier();                                              \
    read_bfrags(lds, boff, wn, 1, l15, l4, bf);                                \
    if (more) stage_half(lds, naoff, Asrc, ROWB, 0, K, kk2, tid);              \
    MFMA_CL(0, 1);                                                             \
    __builtin_amdgcn_s_barrier();                                              \
    read_afrags(lds, aoff, wm, 1, l15, l4, af);                                \
    read_bfrags(lds, boff, wn, 0, l15, l4, bf);                                \
    if (more) stage_half(lds, naoff, Asrc, ROWB, 2, K, kk2, tid);              \
    MFMA_CL(1, 0);                                                             \
    __builtin_amdgcn_s_barrier();                                              \
    read_bfrags(lds, boff, wn, 1, l15, l4, bf);                                \
    MFMA_CL(1, 1);                                                             \
    if (more) {                                                                \
      WAITV(0);                                                                \
      __builtin_amdgcn_s_barrier();                                            \
    }                                                                          \
  }

template<int OUT_MODE, bool RELU>   // 1: bf16+bias(+relu); 0: fp32 partial by z
__global__ __launch_bounds__(512, 2) void k_gemm256(
    const unsigned short* __restrict__ A,
    const unsigned short* __restrict__ Bt,
    const float* __restrict__ bias,
    void* __restrict__ p0, void* __restrict__ p1,
    void* __restrict__ p2, void* __restrict__ p3,
    int M, int N, int K, int KS) {
  extern __shared__ unsigned short lds[];
  int tid = threadIdx.x;
  int wid = tid >> 6, lane = tid & 63;
  int wm = wid >> 2, wn = wid & 3;
  int l15 = lane & 15, l4 = lane >> 4;
  int brow = blockIdx.y * 256, bcol = blockIdx.x * 256;
  int bz = blockIdx.z;
  int kbeg = bz * KS;
  int nk = KS / 64;

  f32x4 acc[8][4];
#pragma unroll
  for (int i = 0; i < 8; i++)
#pragma unroll
    for (int j = 0; j < 4; j++) acc[i][j] = (f32x4){0.f, 0.f, 0.f, 0.f};
  short8 af[4][2], bf[2][2];

  GEMM256_LOOP(A, Bt, brow, bcol);

  if (OUT_MODE == 1) {
    unsigned short* op = (unsigned short*)p0;
#pragma unroll
    for (int ai = 0; ai < 8; ai++)
#pragma unroll
      for (int bj = 0; bj < 4; bj++) {
        int row = brow + wm * 128 + ai * 16 + l4 * 4;
        int col = bcol + wn * 64 + bj * 16 + l15;
        float bs = bias[col];
#pragma unroll
        for (int r = 0; r < 4; r++) {
          float v = acc[ai][bj][r] + bs;
          if (RELU) v = fmaxf(v, 0.f);
          op[(size_t)(row + r) * N + col] = f2bf(v);
        }
      }
  } else {
    float* op = (float*)((bz == 0) ? p0 : (bz == 1) ? p1 : (bz == 2) ? p2 : p3);
#pragma unroll
    for (int ai = 0; ai < 8; ai++)
#pragma unroll
      for (int bj = 0; bj < 4; bj++) {
        int row = brow + wm * 128 + ai * 16 + l4 * 4;
        int col = bcol + wn * 64 + bj * 16 + l15;
#pragma unroll
        for (int r = 0; r < 4; r++)
          op[(size_t)(row + r) * N + col] = acc[ai][bj][r];
      }
  }
}

// ---------------- bf16 GEMM (128-class) --------------------------------------
template<int BM, int OUT_MODE, bool RELU, bool RESID, bool SPLITK>
__global__ __launch_bounds__(256) void k_gemm(
    const unsigned short* __restrict__ A,
    const unsigned short* __restrict__ Bt,
    const float* __restrict__ bias,
    const float* __restrict__ resid,
    void* __restrict__ outp, void* __restrict__ outp2,
    int M, int N, int K, int KS) {
  __shared__ unsigned short Alds[3][BM * 32];
  __shared__ unsigned short Blds[3][128 * 32];
  int tid = threadIdx.x;
  int w = tid >> 6, lane = tid & 63;
  int l15 = lane & 15, l4 = lane >> 4;
  int bxs, bys, bzs;
  xcd_swz(bxs, bys, bzs);
  int brow = bys * BM, bcol = bxs * 128;

  constexpr int MR = 4;
  constexpr int NR = (BM == 128) ? 4 : 2;
  int wr = (BM == 128) ? (w >> 1) : 0;
  int wc = (BM == 128) ? (w & 1) : w;
  int rbase = wr * 64;
  int cbase = wc * (NR * 16);

  f32x4 acc[MR][NR];
#pragma unroll
  for (int i = 0; i < MR; i++)
#pragma unroll
    for (int j = 0; j < NR; j++) acc[i][j] = (f32x4){0.f, 0.f, 0.f, 0.f};

#define STAGEG(bufi, kk) do {                                                  \
    _Pragma("unroll")                                                          \
    for (int c = 0; c < BM / 64; c++) {                                        \
      int elem = (c * 256 + tid) * 8;                                          \
      int row = elem >> 5, col = elem & 31;                                    \
      async16(A + (size_t)(brow + row) * K + (kk) + col, &Alds[bufi][elem]);   \
    }                                                                          \
    _Pragma("unroll")                                                          \
    for (int c = 0; c < 2; c++) {                                              \
      int elem = (c * 256 + tid) * 8;                                          \
      int row = elem >> 5, col = elem & 31;                                    \
      async16(Bt + (size_t)(bcol + row) * K + (kk) + col, &Blds[bufi][elem]);  \
    } } while (0)

  int kbeg = SPLITK ? bzs * KS : 0;
  int nk = KS / 32;
  STAGEG(0, kbeg);
  if (nk > 1) {
    STAGEG(1, kbeg + 32);
    if (BM == 128) WAITV(4); else WAITV(3);
  } else {
    WAITV(0);
  }
  BARRIER_SB();

  for (int t = 0; t < nk; t++) {
    int buf = t % 3;
    if (t + 2 < nk) STAGEG((t + 2) % 3, kbeg + (t + 2) * 32);
    short8 af[MR], bfr[NR];
#pragma unroll
    for (int i = 0; i < MR; i++)
      af[i] = *(const short8*)&Alds[buf][(rbase + i * 16 + l15) * 32 + l4 * 8];
#pragma unroll
    for (int j = 0; j < NR; j++)
      bfr[j] = *(const short8*)&Blds[buf][(cbase + j * 16 + l15) * 32 + l4 * 8];
#pragma unroll
    for (int i = 0; i < MR; i++)
#pragma unroll
      for (int j = 0; j < NR; j++)
        acc[i][j] = __builtin_amdgcn_mfma_f32_16x16x32_bf16(af[i], bfr[j], acc[i][j], 0, 0, 0);
    if (t + 2 < nk) {
      if (BM == 128) WAITV(4); else WAITV(3);
    } else if (t + 1 < nk) {
      WAITV(0);
    }
    if (t + 1 < nk) BARRIER_SB();
  }
#undef STAGEG

  void* op = (SPLITK && bzs) ? outp2 : outp;
#pragma unroll
  for (int i = 0; i < MR; i++)
#pragma unroll
    for (int j = 0; j < NR; j++) {
      int row = brow + rbase + i * 16 + l4 * 4;
      int col = bcol + cbase + j * 16 + l15;
      float bs = (SPLITK || !bias) ? 0.f : bias[col];
#pragma unroll
      for (int r = 0; r < 4; r++) {
        float v = acc[i][j][r] + bs;
        if (RESID) v += resid[(size_t)(row + r) * N + col];
        if (RELU) v = fmaxf(v, 0.f);
        if (OUT_MODE == 0) ((float*)op)[(size_t)(row + r) * N + col] = v;
        else               ((unsigned short*)op)[(size_t)(row + r) * N + col] = f2bf(v);
      }
    }
}

// ---------------- batched 3-mat GEMM, ring-3 ---------------------------------
__global__ __launch_bounds__(256) void k_gemm_qkv(
    const unsigned short* __restrict__ a0, const unsigned short* __restrict__ a1,
    const unsigned short* __restrict__ a2,
    const unsigned short* __restrict__ Bt,
    const float* __restrict__ b0, const float* __restrict__ b1, const float* __restrict__ b2,
    unsigned short* __restrict__ o0, unsigned short* __restrict__ o1, unsigned short* __restrict__ o2,
    int vmat, float qscale, int M, int K) {
  __shared__ unsigned short Alds[3][128 * 32];
  __shared__ unsigned short Blds[3][128 * 32];
  int tid = threadIdx.x;
  int w = tid >> 6, lane = tid & 63;
  int wr = w >> 1, wc = w & 1;
  int l15 = lane & 15, l4 = lane >> 4;
  int bxs, bys, z;
  xcd_swz(bxs, bys, z);
  const unsigned short* A  = (z == 0) ? a0 : (z == 1) ? a1 : a2;
  const unsigned short* Bz = Bt + (size_t)z * 1048576;
  int brow = bys * 128, bcol = bxs * 128;

  f32x4 acc[4][4];
#pragma unroll
  for (int i = 0; i < 4; i++)
#pragma unroll
    for (int j = 0; j < 4; j++) acc[i][j] = (f32x4){0.f, 0.f, 0.f, 0.f};

#define STAGEQ(bufi, kk) do {                                                  \
    _Pragma("unroll")                                                          \
    for (int c = 0; c < 2; c++) {                                              \
      int elem = (c * 256 + tid) * 8;                                          \
      int row = elem >> 5, col = elem & 31;                                    \
      async16(A + (size_t)(brow + row) * K + (kk) + col, &Alds[bufi][elem]);   \
      async16(Bz + (size_t)(bcol + row) * K + (kk) + col, &Blds[bufi][elem]);  \
    } } while (0)

  int nk = K / 32;
  STAGEQ(0, 0);
  STAGEQ(1, 32);
  WAITV(4);
  BARRIER_SB();

  for (int t = 0; t < nk; t++) {
    int buf = t % 3;
    if (t + 2 < nk) STAGEQ((t + 2) % 3, (t + 2) * 32);
    short8 af[4], bfr[4];
#pragma unroll
    for (int i = 0; i < 4; i++) {
      af[i]  = *(const short8*)&Alds[buf][(wr * 64 + i * 16 + l15) * 32 + l4 * 8];
      bfr[i] = *(const short8*)&Blds[buf][(wc * 64 + i * 16 + l15) * 32 + l4 * 8];
    }
#pragma unroll
    for (int i = 0; i < 4; i++)
#pragma unroll
      for (int j = 0; j < 4; j++)
        acc[i][j] = __builtin_amdgcn_mfma_f32_16x16x32_bf16(af[i], bfr[j], acc[i][j], 0, 0, 0);
    if (t + 2 < nk) WAITV(4);
    else if (t + 1 < nk) WAITV(0);
    if (t + 1 < nk) BARRIER_SB();
  }
#undef STAGEQ

  const float* bias = (z == 0) ? b0 : (z == 1) ? b1 : b2;
  unsigned short* op = (z == 0) ? o0 : (z == 1) ? o1 : o2;
  bool tr = (z == vmat);
#pragma unroll
  for (int i = 0; i < 4; i++)
#pragma unroll
    for (int j = 0; j < 4; j++) {
      int row = brow + wr * 64 + i * 16 + l4 * 4;
      int colL = bcol + wc * 64 + j * 16 + l15;
      float bs = bias[colL];
#pragma unroll
      for (int r = 0; r < 4; r++) {
        float v = acc[i][j][r] + bs;
        if (z == 0) v *= qscale;
        if (tr) op[(size_t)colL * M + row + r] = f2bf(v);
        else    op[(size_t)(row + r) * 1024 + colL] = f2bf(v);
      }
    }
}

// ---------------- flash attention (4-wave, 64 q-rows, ring-2 K/V) ------------
// NF=1: grid (32, NH, B) = 1024 blocks; LDS 41.2 KB -> 3 blocks/CU.
// CAUSAL: qt = 31-bx (heavy blocks dispatch first, LPT balance).
template<bool CAUSAL, int NF>
__global__ __launch_bounds__(256) void k_attn(
    const unsigned short* __restrict__ Q,
    const unsigned short* __restrict__ Kb,
    const unsigned short* __restrict__ Vt,
    const float* __restrict__ pm,     // [B][S] padding mask or null
    unsigned short* __restrict__ out) {
  __shared__ unsigned short Klds[2][64 * 64];
  __shared__ unsigned short Vlds[2][64 * 64];
  __shared__ unsigned short Pw[4][NF][16 * 72];
  int tid = threadIdx.x, w = tid >> 6, lane = tid & 63;
  int l15 = lane & 15, l4 = lane >> 4;
  int h = blockIdx.y, b = blockIdx.z;

#define STAGE(bufi, kt_) do {                                                  \
    _Pragma("unroll")                                                          \
    for (int c = 0; c < 2; c++) {                                              \
      int e0 = w * 1024 + c * 512;                                             \
      int elem = e0 + lane * 8;                                                \
      int row_ = elem >> 6;                                                    \
      int col_ = (elem & 63) ^ ((row_ & 7) << 3);                              \
      async16(Kb + (size_t)(b * SS + (kt_) * 64 + row_) * DM + h * 64 + col_,  \
              &Klds[bufi][elem]);                                              \
      async16(Vt + (size_t)(h * 64 + row_) * MT + b * SS + (kt_) * 64 + col_,  \
              &Vlds[bufi][elem]);                                              \
    } } while (0)

  int qt = CAUSAL ? ((int)gridDim.x - 1 - (int)blockIdx.x) : (int)blockIdx.x;
  int qbase = qt * (NF * 64) + w * (NF * 16);

  short8 qf[NF][2];
#pragma unroll
  for (int f = 0; f < NF; f++) {
    size_t qrow = (size_t)b * SS + qbase + f * 16 + l15;
#pragma unroll
    for (int ks = 0; ks < 2; ks++)
      qf[f][ks] = *(const short8*)(Q + qrow * DM + h * 64 + ks * 32 + l4 * 8);
  }

  float mrow[NF], lrow[NF];
  f32x4 accO[NF][4];
#pragma unroll
  for (int f = 0; f < NF; f++) {
    mrow[f] = -1e30f; lrow[f] = 0.f;
#pragma unroll
    for (int d = 0; d < 4; d++) accO[f][d] = (f32x4){0.f, 0.f, 0.f, 0.f};
  }

  int ktend = CAUSAL ? qt : (SS / 64 - 1);
  STAGE(0, 0);
  WAITV(0);
  BARRIER_SB();

  for (int kt = 0; kt <= ktend; kt++) {
    int buf = kt & 1;
    bool more = (kt + 1 <= ktend);
    if (more) STAGE(buf ^ 1, kt + 1);   // early issue; drain at tile end

    {
      f32x4 sa[NF][4];
#pragma unroll
      for (int f = 0; f < NF; f++)
#pragma unroll
        for (int nt = 0; nt < 4; nt++) sa[f][nt] = (f32x4){0.f, 0.f, 0.f, 0.f};
      __builtin_amdgcn_s_setprio(1);
#pragma unroll
      for (int ks = 0; ks < 2; ks++)
#pragma unroll
        for (int nt = 0; nt < 4; nt++) {
          int kr = nt * 16 + l15;
          short8 kf = *(const short8*)&Klds[buf][kr * 64 + ((ks * 32 + l4 * 8) ^ ((kr & 7) << 3))];
#pragma unroll
          for (int f = 0; f < NF; f++)
            sa[f][nt] = __builtin_amdgcn_mfma_f32_16x16x32_bf16(kf, qf[f][ks], sa[f][nt], 0, 0, 0);
        }
      __builtin_amdgcn_s_setprio(0);

      float pmb[16];
      if (!CAUSAL) {
#pragma unroll
        for (int nt = 0; nt < 4; nt++) {
          float4 pmv = *(const float4*)(pm + b * SS + kt * 64 + nt * 16 + l4 * 4);
#pragma unroll
          for (int r = 0; r < 4; r++) pmb[nt * 4 + r] = ((const float*)&pmv)[r] * -1e30f;
        }
      }
      bool diag = CAUSAL && (kt * 64 + 63 > qbase);

      // ---- scores (Q pre-scaled) + per-lane max3 tree
      float sv[NF][16], tm[NF];
#pragma unroll
      for (int f = 0; f < NF; f++) {
        if (CAUSAL && !diag) {
#pragma unroll
          for (int i = 0; i < 16; i++) sv[f][i] = sa[f][i >> 2][i & 3];
        } else if (CAUSAL) {
#pragma unroll
          for (int nt = 0; nt < 4; nt++)
#pragma unroll
            for (int r = 0; r < 4; r++) {
              float s = sa[f][nt][r];
              int kg = kt * 64 + nt * 16 + l4 * 4 + r;
              int qg = qbase + f * 16 + l15;
              if (kg > qg) s = -1e30f;
              sv[f][nt * 4 + r] = s;
            }
        } else {
#pragma unroll
          for (int i = 0; i < 16; i++)
            sv[f][i] = sa[f][i >> 2][i & 3] + pmb[i];
        }
        tm[f] = max16(sv[f]);
      }

      // ---- cross-lane row max
      float sA[NF];
#pragma unroll
      for (int f = 0; f < NF; f++) sA[f] = swz16(tm[f]);
#pragma unroll
      for (int f = 0; f < NF; f++) tm[f] = fmaxf(tm[f], sA[f]);
      float xA[NF];
#pragma unroll
      for (int f = 0; f < NF; f++) xA[f] = __shfl_xor(tm[f], 32);
#pragma unroll
      for (int f = 0; f < NF; f++) tm[f] = fmaxf(tm[f], xA[f]);

#pragma unroll
      for (int f = 0; f < NF; f++) {
        if (!__all(tm[f] - mrow[f] <= 8.f)) {
          float mnew = fmaxf(mrow[f], tm[f]);
          float corr = EXP2(mrow[f] - mnew);
          mrow[f] = mnew;
          lrow[f] *= corr;
#pragma unroll
          for (int r = 0; r < 4; r++) {
            float cq = __shfl(corr, l4 * 4 + r);
#pragma unroll
            for (int dt = 0; dt < 4; dt++) accO[f][dt][r] *= cq;
          }
        }

        float p[16];
#pragma unroll
        for (int i = 0; i < 16; i++) p[i] = EXP2(sv[f][i] - mrow[f]);
        float a8[8];
#pragma unroll
        for (int i = 0; i < 8; i++) a8[i] = p[i] + p[i + 8];
#pragma unroll
        for (int i = 0; i < 4; i++) a8[i] = a8[i] + a8[i + 4];
        lrow[f] += (a8[0] + a8[1]) + (a8[2] + a8[3]);

#pragma unroll
        for (int nt = 0; nt < 4; nt++) {
          uint2 u;
          u.x = cvt_pk_bf16(p[nt * 4 + 0], p[nt * 4 + 1]);
          u.y = cvt_pk_bf16(p[nt * 4 + 2], p[nt * 4 + 3]);
          *(uint2*)&Pw[w][f][l15 * 72 + nt * 16 + l4 * 4] = u;
        }
      }

      __builtin_amdgcn_s_setprio(1);
#pragma unroll
      for (int ks = 0; ks < 2; ks++) {
        short8 pf[NF];
#pragma unroll
        for (int f = 0; f < NF; f++)
          pf[f] = *(const short8*)&Pw[w][f][l15 * 72 + ks * 32 + l4 * 8];
#pragma unroll
        for (int dt = 0; dt < 4; dt++) {
          int vr = dt * 16 + l15;
          short8 vf = *(const short8*)&Vlds[buf][vr * 64 + ((ks * 32 + l4 * 8) ^ ((vr & 7) << 3))];
#pragma unroll
          for (int f = 0; f < NF; f++)
            accO[f][dt] = __builtin_amdgcn_mfma_f32_16x16x32_bf16(pf[f], vf, accO[f][dt], 0, 0, 0);
        }
      }
      __builtin_amdgcn_s_setprio(0);
    }

    if (more) {
      WAITV(0);        // next tile fully in LDS
      BARRIER_SB();
    }
  }

#pragma unroll
  for (int f = 0; f < NF; f++) {
    lrow[f] += swz16(lrow[f]);
    lrow[f] += __shfl_xor(lrow[f], 32);
  }
#pragma unroll
  for (int f = 0; f < NF; f++)
#pragma unroll
    for (int r = 0; r < 4; r++) {
      float lq = __shfl(lrow[f], l4 * 4 + r);
      float inv = 1.f / lq;
      size_t row = (size_t)b * SS + qbase + f * 16 + l4 * 4 + r;
#pragma unroll
      for (int dt = 0; dt < 4; dt++)
        out[row * DM + h * 64 + dt * 16 + l15] = f2bf(accO[f][dt][r] * inv);
    }
#undef STAGE
}

// ---------------- LayerNorm over D=1024, one block per row --------------------
__global__ __launch_bounds__(256) void k_ln(
    const float* __restrict__ in, const float* __restrict__ in2,
    const float* __restrict__ in3, const float* __restrict__ in4,
    const float* __restrict__ resid, const float* __restrict__ bias,
    const float* __restrict__ g, const float* __restrict__ bb,
    float* __restrict__ outf, unsigned short* __restrict__ outb) {
  int row = blockIdx.x, tid = threadIdx.x;
  int w = tid >> 6;
  __shared__ float red[4];
  float4 v = *(const float4*)(in + (size_t)row * 1024 + tid * 4);
  if (in2) {
    float4 v2 = *(const float4*)(in2 + (size_t)row * 1024 + tid * 4);
    v.x += v2.x; v.y += v2.y; v.z += v2.z; v.w += v2.w;
  }
  if (in3) {
    float4 v2 = *(const float4*)(in3 + (size_t)row * 1024 + tid * 4);
    v.x += v2.x; v.y += v2.y; v.z += v2.z; v.w += v2.w;
  }
  if (in4) {
    float4 v2 = *(const float4*)(in4 + (size_t)row * 1024 + tid * 4);
    v.x += v2.x; v.y += v2.y; v.z += v2.z; v.w += v2.w;
  }
  if (resid) {
    float4 v2 = *(const float4*)(resid + (size_t)row * 1024 + tid * 4);
    v.x += v2.x; v.y += v2.y; v.z += v2.z; v.w += v2.w;
  }
  if (bias) {
    float4 v2 = *(const float4*)(bias + tid * 4);
    v.x += v2.x; v.y += v2.y; v.z += v2.z; v.w += v2.w;
  }
  float s = v.x + v.y + v.z + v.w;
#pragma unroll
  for (int d = 1; d < 64; d <<= 1) s += __shfl_xor(s, d);
  if ((tid & 63) == 0) red[w] = s;
  __syncthreads();
  float mu = (red[0] + red[1] + red[2] + red[3]) * (1.f / 1024.f);
  float d0 = v.x - mu, d1 = v.y - mu, d2 = v.z - mu, d3 = v.w - mu;
  float q = d0 * d0 + d1 * d1 + d2 * d2 + d3 * d3;
#pragma unroll
  for (int d = 1; d < 64; d <<= 1) q += __shfl_xor(q, d);
  __syncthreads();
  if ((tid & 63) == 0) red[w] = q;
  __syncthreads();
  float var = (red[0] + red[1] + red[2] + red[3]) * (1.f / 1024.f);
  float rs = rsqrtf(var + 1e-6f);
  float4 gg = *(const float4*)(g + tid * 4);
  float4 bv = *(const float4*)(bb + tid * 4);
  float y0 = d0 * rs * gg.x + bv.x;
  float y1 = d1 * rs * gg.y + bv.y;
  float y2 = d2 * rs * gg.z + bv.z;
  float y3 = d3 * rs * gg.w + bv.w;
  if (outf) {
    float4 o; o.x = y0; o.y = y1; o.z = y2; o.w = y3;
    *(float4*)(outf + (size_t)row * 1024 + tid * 4) = o;
  }
  if (outb) {
    uint2 u;
    u.x = (unsigned)f2bf(y0) | ((unsigned)f2bf(y1) << 16);
    u.y = (unsigned)f2bf(y2) | ((unsigned)f2bf(y3) << 16);
    *(uint2*)(outb + (size_t)row * 1024 + tid * 4) = u;
  }
}

extern "C" void kernel_launch(void* const* d_in, const int* in_sizes, int n_in,
                              void* d_out, int out_size, void* d_ws, size_t ws_size,
                              hipStream_t stream) {
  const float* x    = (const float*)d_in[0];
  const float* enc  = (const float*)d_in[1];
  const float* pm   = (const float*)d_in[3];
  const float* wq1  = (const float*)d_in[4];   const float* bq1 = (const float*)d_in[5];
  const float* wk1  = (const float*)d_in[6];   const float* bk1 = (const float*)d_in[7];
  const float* wv1  = (const float*)d_in[8];   const float* bv1 = (const float*)d_in[9];
  const float* wo1  = (const float*)d_in[10];  const float* bo1 = (const float*)d_in[11];
  const float* wq2  = (const float*)d_in[12];  const float* bq2 = (const float*)d_in[13];
  const float* wk2  = (const float*)d_in[14];  const float* bk2 = (const float*)d_in[15];
  const float* wv2  = (const float*)d_in[16];  const float* bv2 = (const float*)d_in[17];
  const float* wo2  = (const float*)d_in[18];  const float* bo2 = (const float*)d_in[19];
  const float* fw1  = (const float*)d_in[20];  const float* fb1 = (const float*)d_in[21];
  const float* fw2  = (const float*)d_in[22];  const float* fb2 = (const float*)d_in[23];
  const float* ln1g = (const float*)d_in[24];  const float* ln1b = (const float*)d_in[25];
  const float* ln2g = (const float*)d_in[26];  const float* ln2b = (const float*)d_in[27];
  const float* ln3g = (const float*)d_in[28];  const float* ln3b = (const float*)d_in[29];

  char* ws = (char*)d_ws;
  unsigned short* XB = (unsigned short*)(ws + 0);          // 8.39 MB
  unsigned short* EB = (unsigned short*)(ws + 8388608);
  unsigned short* Qb = (unsigned short*)(ws + 16777216);
  unsigned short* Kb = (unsigned short*)(ws + 25165824);
  unsigned short* Vt = (unsigned short*)(ws + 33554432);   // [DM][MT]
  unsigned short* AT = (unsigned short*)(ws + 41943040);
  float*          T  = (float*)(ws + 50331648);            // 16.78 MB
  float*          R  = (float*)(ws + 67108864);            // 16.78 MB
  unsigned short* RB = (unsigned short*)(ws + 83886080);
  unsigned short* WT0 = (unsigned short*)(ws + 92274688);  // 8 x 2 MB
  unsigned short* W1T = (unsigned short*)(ws + 92274688 + 16777216);  // 8.39 MB
  unsigned short* W2T = (unsigned short*)(ws + 92274688 + 25165824);  // 8.39 MB
  unsigned short* H   = (unsigned short*)(ws + 0);         // overlaps XB..Kb (dead then)
  float*          T1o = (float*)(ws + 16777216);           // overlaps Qb+Kb (dead at O-proj)
  // FFN2 4-way split-K partials (regions dead at FFN2 time):
  float*          P0  = T;
  float*          P1  = (float*)(ws + 33554432);
  float*          P2  = (float*)(ws + 83886080);
  float*          P3  = (float*)(ws + 100663296);

  // ---- conversions ----
  k_conv2<<<8192, 256, 0, stream>>>(x, enc, XB, EB);
  PtrArr ptrs;
  ptrs.p[0] = wq1; ptrs.p[1] = wk1; ptrs.p[2] = wv1; ptrs.p[3] = wo1;
  ptrs.p[4] = wq2; ptrs.p[5] = wk2; ptrs.p[6] = wv2; ptrs.p[7] = wo2;
  k_transpose8<<<dim3(16, 16, 8), 256, 0, stream>>>(ptrs, WT0);
  k_transpose_bf16<<<dim3(64, 16), 256, 0, stream>>>(fw1, W1T, 1024, 4096);
  k_transpose_bf16<<<dim3(16, 64), 256, 0, stream>>>(fw2, W2T, 4096, 1024);

  hipError_t e1 = hipFuncSetAttribute(
      reinterpret_cast<const void*>(k_gemm256<1, true>),
      hipFuncAttributeMaxDynamicSharedMemorySize, 131072);
  hipError_t e2 = hipFuncSetAttribute(
      reinterpret_cast<const void*>(k_gemm256<0, false>),
      hipFuncAttributeMaxDynamicSharedMemorySize, 131072);
  bool big = (e1 == hipSuccess && e2 == hipSuccess);

  // ---- self attention ----
  k_gemm_qkv<<<dim3(8, 32, 3), 256, 0, stream>>>(XB, XB, XB, WT0, bq1, bk1, bv1,
                                                 Qb, Kb, Vt, 2, QSCALE, MT, DM);
  k_attn<true, 1><<<dim3(32, 16, 2), 256, 0, stream>>>(Qb, Kb, Vt, nullptr, AT);
  k_gemm<64, 0, false, false, true><<<dim3(8, 64, 2), 256, 0, stream>>>(
      AT, WT0 + 3 * 1048576, nullptr, nullptr, T, T1o, MT, DM, DM, 512);
  k_ln<<<4096, 256, 0, stream>>>(T, T1o, nullptr, nullptr, x, bo1, ln1g, ln1b, R, RB);

  // ---- cross attention ----
  k_gemm_qkv<<<dim3(8, 32, 3), 256, 0, stream>>>(RB, EB, EB, WT0 + 4 * 1048576,
                                                 bq2, bk2, bv2, Qb, Kb, Vt, 2, QSCALE, MT, DM);
  k_attn<false, 1><<<dim3(32, 16, 2), 256, 0, stream>>>(Qb, Kb, Vt, pm, AT);
  k_gemm<64, 0, false, false, true><<<dim3(8, 64, 2), 256, 0, stream>>>(
      AT, WT0 + 7 * 1048576, nullptr, nullptr, T, T1o, MT, DM, DM, 512);
  k_ln<<<4096, 256, 0, stream>>>(T, T1o, nullptr, nullptr, R, bo2, ln2g, ln2b, R, RB);

  // ---- FFN ----
  if (big) {
    k_gemm256<1, true><<<dim3(16, 16, 1), 512, 131072, stream>>>(
        RB, W1T, fb1, H, nullptr, nullptr, nullptr, MT, 4096, DM, DM);
    k_gemm256<0, false><<<dim3(4, 16, 4), 512, 131072, stream>>>(
        H, W2T, nullptr, P0, P1, P2, P3, MT, DM, 4096, 1024);
    k_ln<<<4096, 256, 0, stream>>>(P0, P1, P2, P3, R, fb2, ln3g, ln3b,
                                   (float*)d_out, nullptr);
  } else {
    k_gemm<128, 1, true, false, false><<<dim3(32, 32), 256, 0, stream>>>(
        RB, W1T, fb1, nullptr, H, nullptr, MT, 4096, DM, 1024);
    k_gemm<64, 0, false, false, true><<<dim3(8, 64, 2), 256, 0, stream>>>(
        H, W2T, nullptr, nullptr, T, (float*)(ws + 33554432), MT, DM, 4096, 2048);
    k_ln<<<4096, 256, 0, stream>>>(T, (float*)(ws + 33554432), nullptr, nullptr,
                                   R, fb2, ln3g, ln3b, (float*)d_out, nullptr);
  }
}

// Round 17
// 424.728 us; speedup vs baseline: 1.1599x; 1.1599x over previous
//
#include <hip/hip_runtime.h>
#include <hip/hip_bf16.h>
#include <stdint.h>

#define DM   1024
#define NH   16
#define SS   2048
#define BB   2
#define MT   4096   // B*S

typedef __attribute__((ext_vector_type(8))) short short8;
typedef __attribute__((ext_vector_type(4))) float f32x4;

typedef __attribute__((address_space(1))) const unsigned int as1_uint;
typedef __attribute__((address_space(3))) unsigned int as3_uint;

__device__ __forceinline__ void async16(const void* g, void* l) {
  __builtin_amdgcn_global_load_lds((as1_uint*)g, (as3_uint*)l, 16, 0, 0);
}

#define WAITV(n) asm volatile("s_waitcnt vmcnt(" #n ")" ::: "memory")
#define BARRIER_SB() do { __builtin_amdgcn_s_barrier(); __builtin_amdgcn_sched_barrier(0); } while (0)
#define EXP2(x) __builtin_amdgcn_exp2f(x)
#define QSCALE 0.180336879f   // 0.125 * log2(e)

__device__ __forceinline__ unsigned short f2bf(float f) {
  union { float f; unsigned u; } c; c.f = f;
  unsigned r = c.u + 0x7fffu + ((c.u >> 16) & 1u);
  return (unsigned short)(r >> 16);
}

__device__ __forceinline__ unsigned cvt_pk_bf16(float lo, float hi) {
  unsigned r;
  asm("v_cvt_pk_bf16_f32 %0, %1, %2" : "=v"(r) : "v"(lo), "v"(hi));
  return r;
}

__device__ __forceinline__ float swz16(float x) {
  return __uint_as_float((unsigned)__builtin_amdgcn_ds_swizzle((int)__float_as_uint(x), 0x401F));
}

// 16-way max with v_max3-fusable triples
__device__ __forceinline__ float max16(const float* s) {
  float a = fmaxf(fmaxf(s[0], s[1]), s[2]);
  float b = fmaxf(fmaxf(s[3], s[4]), s[5]);
  float c = fmaxf(fmaxf(s[6], s[7]), s[8]);
  float d = fmaxf(fmaxf(s[9], s[10]), s[11]);
  float e = fmaxf(fmaxf(s[12], s[13]), s[14]);
  float ab = fmaxf(fmaxf(a, b), c);
  float de = fmaxf(fmaxf(d, e), s[15]);
  return fmaxf(ab, de);
}

__device__ __forceinline__ void xcd_swz(int& bx, int& by, int& bz) {
  int GX = gridDim.x, GY = gridDim.y;
  int nwg = GX * GY * gridDim.z;
  int old = blockIdx.x + GX * (blockIdx.y + GY * blockIdx.z);
  int f2 = (old & 7) * (nwg >> 3) + (old >> 3);
  bz = f2 / (GX * GY);
  int rem = f2 % (GX * GY);
  bx = rem / GY;
  by = rem % GY;
}

// ---------------- fp32 -> bf16 convert (x and enc in one launch) -------------
__global__ __launch_bounds__(256) void k_conv2(
    const float* __restrict__ a, const float* __restrict__ b,
    unsigned short* __restrict__ oa, unsigned short* __restrict__ ob) {
  int bxr = blockIdx.x;
  const float* in = (bxr < 4096) ? a : b;
  unsigned short* out = (bxr < 4096) ? oa : ob;
  int i = ((bxr & 4095) * 256 + threadIdx.x) * 4;
  float4 v = *(const float4*)(in + i);
  uint2 u;
  u.x = (unsigned)f2bf(v.x) | ((unsigned)f2bf(v.y) << 16);
  u.y = (unsigned)f2bf(v.z) | ((unsigned)f2bf(v.w) << 16);
  *(uint2*)(out + i) = u;
}

// ---------------- fp32 [R][C] -> bf16 [C][R] transpose-convert ----------------
__global__ __launch_bounds__(256) void k_transpose_bf16(
    const float* __restrict__ in, unsigned short* __restrict__ out, int R, int C) {
  __shared__ float t[64][65];
  int c0 = blockIdx.x * 64, r0 = blockIdx.y * 64;
  int tx = threadIdx.x & 63, ty = threadIdx.x >> 6;  // 64 x 4
#pragma unroll
  for (int i = 0; i < 16; i++)
    t[ty + i * 4][tx] = in[(size_t)(r0 + ty + i * 4) * C + c0 + tx];
  __syncthreads();
#pragma unroll
  for (int i = 0; i < 16; i++)
    out[(size_t)(c0 + ty + i * 4) * R + r0 + tx] = f2bf(t[tx][ty + i * 4]);
}

struct PtrArr { const float* p[8]; };
__global__ __launch_bounds__(256) void k_transpose8(
    PtrArr ps, unsigned short* __restrict__ out0) {
  __shared__ float t[64][65];
  const float* in = ps.p[blockIdx.z];
  unsigned short* out = out0 + (size_t)blockIdx.z * 1048576;
  int c0 = blockIdx.x * 64, r0 = blockIdx.y * 64;
  int tx = threadIdx.x & 63, ty = threadIdx.x >> 6;
#pragma unroll
  for (int i = 0; i < 16; i++)
    t[ty + i * 4][tx] = in[(size_t)(r0 + ty + i * 4) * 1024 + c0 + tx];
  __syncthreads();
#pragma unroll
  for (int i = 0; i < 16; i++)
    out[(size_t)(c0 + ty + i * 4) * 1024 + r0 + tx] = f2bf(t[tx][ty + i * 4]);
}

// ---------------- 256x256 BK=64 8-wave phase-split GEMM core -----------------
__device__ __forceinline__ void stage_half(
    unsigned short* lds, int dst_off, const unsigned short* __restrict__ src,
    int sbase, int c0, int K, int kk, int tid) {
#pragma unroll
  for (int c = 0; c < 2; c++) {
    int e = ((c0 + c) * 512 + tid) * 8;
    int r_ = e >> 6, s_ = e & 63;
    async16(src + (size_t)(sbase + r_) * K + kk + (s_ ^ ((r_ & 4) << 2)),
            &lds[dst_off + e]);
  }
}

__device__ __forceinline__ void read_afrags(
    const unsigned short* lds, int aoff, int wm, int rh, int l15, int l4,
    short8 af[4][2]) {
#pragma unroll
  for (int i = 0; i < 4; i++) {
    int arow = wm * 128 + rh * 64 + i * 16 + l15;
#pragma unroll
    for (int ks = 0; ks < 2; ks++)
      af[i][ks] = *(const short8*)&lds[aoff + arow * 64 +
          ((ks * 32 + l4 * 8) ^ ((arow & 4) << 2))];
  }
}

__device__ __forceinline__ void read_bfrags(
    const unsigned short* lds, int boff, int wn, int ch, int l15, int l4,
    short8 bf[2][2]) {
#pragma unroll
  for (int j = 0; j < 2; j++) {
    int brw = wn * 64 + ch * 32 + j * 16 + l15;
#pragma unroll
    for (int ks = 0; ks < 2; ks++)
      bf[j][ks] = *(const short8*)&lds[boff + brw * 64 +
          ((ks * 32 + l4 * 8) ^ ((brw & 4) << 2))];
  }
}

#define MFMA_CL(RH, CH)                                                        \
  __builtin_amdgcn_s_barrier();                                                \
  asm volatile("s_waitcnt lgkmcnt(0)" ::: "memory");                           \
  __builtin_amdgcn_sched_barrier(0);                                           \
  __builtin_amdgcn_s_setprio(1);                                               \
  _Pragma("unroll")                                                            \
  for (int ks = 0; ks < 2; ks++)                                               \
    _Pragma("unroll")                                                          \
    for (int i = 0; i < 4; i++)                                                \
      _Pragma("unroll")                                                        \
      for (int j = 0; j < 2; j++)                                              \
        acc[(RH) * 4 + i][(CH) * 2 + j] =                                      \
            __builtin_amdgcn_mfma_f32_16x16x32_bf16(                           \
                af[i][ks], bf[j][ks], acc[(RH) * 4 + i][(CH) * 2 + j], 0, 0, 0); \
  __builtin_amdgcn_s_setprio(0);

#define GEMM256_LOOP(Asrc, Bsrc, ROWB, COLB)                                   \
  stage_half(lds, 32768, Bsrc, COLB, 0, K, kbeg, tid);                         \
  stage_half(lds, 32768, Bsrc, COLB, 2, K, kbeg, tid);                         \
  stage_half(lds, 0,     Asrc, ROWB, 0, K, kbeg, tid);                         \
  stage_half(lds, 0,     Asrc, ROWB, 2, K, kbeg, tid);                         \
  WAITV(0);                                                                    \
  __builtin_amdgcn_s_barrier();                                                \
  for (int t = 0; t < nk; t++) {                                               \
    int buf = t & 1, nb = buf ^ 1;                                             \
    int aoff = buf * 16384, boff = 32768 + buf * 16384;                        \
    int naoff = nb * 16384, nboff = 32768 + nb * 16384;                        \
    int kk2 = kbeg + (t + 1) * 64;                                             \
    bool more = (t + 1 < nk);                                                  \
    read_afrags(lds, aoff, wm, 0, l15, l4, af);                                \
    read_bfrags(lds, boff, wn, 0, l15, l4, bf);                                \
    if (more) {                                                                \
      stage_half(lds, nboff, Bsrc, COLB, 0, K, kk2, tid);                      \
      stage_half(lds, nboff, Bsrc, COLB, 2, K, kk2, tid);                      \
    }                                                                          \
    MFMA_CL(0, 0);                                                             \
    __builtin_amdgcn_s_barrier();                                              \
    read_bfrags(lds, boff, wn, 1, l15, l4, bf);                                \
    if (more) stage_half(lds, naoff, Asrc, ROWB, 0, K, kk2, tid);              \
    MFMA_CL(0, 1);                                                             \
    __builtin_amdgcn_s_barrier();                                              \
    read_afrags(lds, aoff, wm, 1, l15, l4, af);                                \
    read_bfrags(lds, boff, wn, 0, l15, l4, bf);                                \
    if (more) stage_half(lds, naoff, Asrc, ROWB, 2, K, kk2, tid);              \
    MFMA_CL(1, 0);                                                             \
    __builtin_amdgcn_s_barrier();                                              \
    read_bfrags(lds, boff, wn, 1, l15, l4, bf);                                \
    MFMA_CL(1, 1);                                                             \
    if (more) {                                                                \
      WAITV(0);                                                                \
      __builtin_amdgcn_s_barrier();                                            \
    }                                                                          \
  }

template<int OUT_MODE, bool RELU>   // 1: bf16+bias(+relu); 0: fp32 partial by z
__global__ __launch_bounds__(512, 2) void k_gemm256(
    const unsigned short* __restrict__ A,
    const unsigned short* __restrict__ Bt,
    const float* __restrict__ bias,
    void* __restrict__ p0, void* __restrict__ p1,
    void* __restrict__ p2, void* __restrict__ p3,
    int M, int N, int K, int KS) {
  extern __shared__ unsigned short lds[];
  int tid = threadIdx.x;
  int wid = tid >> 6, lane = tid & 63;
  int wm = wid >> 2, wn = wid & 3;
  int l15 = lane & 15, l4 = lane >> 4;
  int brow = blockIdx.y * 256, bcol = blockIdx.x * 256;
  int bz = blockIdx.z;
  int kbeg = bz * KS;
  int nk = KS / 64;

  f32x4 acc[8][4];
#pragma unroll
  for (int i = 0; i < 8; i++)
#pragma unroll
    for (int j = 0; j < 4; j++) acc[i][j] = (f32x4){0.f, 0.f, 0.f, 0.f};
  short8 af[4][2], bf[2][2];

  GEMM256_LOOP(A, Bt, brow, bcol);

  if (OUT_MODE == 1) {
    unsigned short* op = (unsigned short*)p0;
#pragma unroll
    for (int ai = 0; ai < 8; ai++)
#pragma unroll
      for (int bj = 0; bj < 4; bj++) {
        int row = brow + wm * 128 + ai * 16 + l4 * 4;
        int col = bcol + wn * 64 + bj * 16 + l15;
        float bs = bias[col];
#pragma unroll
        for (int r = 0; r < 4; r++) {
          float v = acc[ai][bj][r] + bs;
          if (RELU) v = fmaxf(v, 0.f);
          op[(size_t)(row + r) * N + col] = f2bf(v);
        }
      }
  } else {
    float* op = (float*)((bz == 0) ? p0 : (bz == 1) ? p1 : (bz == 2) ? p2 : p3);
#pragma unroll
    for (int ai = 0; ai < 8; ai++)
#pragma unroll
      for (int bj = 0; bj < 4; bj++) {
        int row = brow + wm * 128 + ai * 16 + l4 * 4;
        int col = bcol + wn * 64 + bj * 16 + l15;
#pragma unroll
        for (int r = 0; r < 4; r++)
          op[(size_t)(row + r) * N + col] = acc[ai][bj][r];
      }
  }
}

// ---------------- bf16 GEMM (128-class) --------------------------------------
template<int BM, int OUT_MODE, bool RELU, bool RESID, bool SPLITK>
__global__ __launch_bounds__(256) void k_gemm(
    const unsigned short* __restrict__ A,
    const unsigned short* __restrict__ Bt,
    const float* __restrict__ bias,
    const float* __restrict__ resid,
    void* __restrict__ outp, void* __restrict__ outp2,
    int M, int N, int K, int KS) {
  __shared__ unsigned short Alds[3][BM * 32];
  __shared__ unsigned short Blds[3][128 * 32];
  int tid = threadIdx.x;
  int w = tid >> 6, lane = tid & 63;
  int l15 = lane & 15, l4 = lane >> 4;
  int bxs, bys, bzs;
  xcd_swz(bxs, bys, bzs);
  int brow = bys * BM, bcol = bxs * 128;

  constexpr int MR = 4;
  constexpr int NR = (BM == 128) ? 4 : 2;
  int wr = (BM == 128) ? (w >> 1) : 0;
  int wc = (BM == 128) ? (w & 1) : w;
  int rbase = wr * 64;
  int cbase = wc * (NR * 16);

  f32x4 acc[MR][NR];
#pragma unroll
  for (int i = 0; i < MR; i++)
#pragma unroll
    for (int j = 0; j < NR; j++) acc[i][j] = (f32x4){0.f, 0.f, 0.f, 0.f};

#define STAGEG(bufi, kk) do {                                                  \
    _Pragma("unroll")                                                          \
    for (int c = 0; c < BM / 64; c++) {                                        \
      int elem = (c * 256 + tid) * 8;                                          \
      int row = elem >> 5, col = elem & 31;                                    \
      async16(A + (size_t)(brow + row) * K + (kk) + col, &Alds[bufi][elem]);   \
    }                                                                          \
    _Pragma("unroll")                                                          \
    for (int c = 0; c < 2; c++) {                                              \
      int elem = (c * 256 + tid) * 8;                                          \
      int row = elem >> 5, col = elem & 31;                                    \
      async16(Bt + (size_t)(bcol + row) * K + (kk) + col, &Blds[bufi][elem]);  \
    } } while (0)

  int kbeg = SPLITK ? bzs * KS : 0;
  int nk = KS / 32;
  STAGEG(0, kbeg);
  if (nk > 1) {
    STAGEG(1, kbeg + 32);
    if (BM == 128) WAITV(4); else WAITV(3);
  } else {
    WAITV(0);
  }
  BARRIER_SB();

  for (int t = 0; t < nk; t++) {
    int buf = t % 3;
    if (t + 2 < nk) STAGEG((t + 2) % 3, kbeg + (t + 2) * 32);
    short8 af[MR], bfr[NR];
#pragma unroll
    for (int i = 0; i < MR; i++)
      af[i] = *(const short8*)&Alds[buf][(rbase + i * 16 + l15) * 32 + l4 * 8];
#pragma unroll
    for (int j = 0; j < NR; j++)
      bfr[j] = *(const short8*)&Blds[buf][(cbase + j * 16 + l15) * 32 + l4 * 8];
#pragma unroll
    for (int i = 0; i < MR; i++)
#pragma unroll
      for (int j = 0; j < NR; j++)
        acc[i][j] = __builtin_amdgcn_mfma_f32_16x16x32_bf16(af[i], bfr[j], acc[i][j], 0, 0, 0);
    if (t + 2 < nk) {
      if (BM == 128) WAITV(4); else WAITV(3);
    } else if (t + 1 < nk) {
      WAITV(0);
    }
    if (t + 1 < nk) BARRIER_SB();
  }
#undef STAGEG

  void* op = (SPLITK && bzs) ? outp2 : outp;
#pragma unroll
  for (int i = 0; i < MR; i++)
#pragma unroll
    for (int j = 0; j < NR; j++) {
      int row = brow + rbase + i * 16 + l4 * 4;
      int col = bcol + cbase + j * 16 + l15;
      float bs = (SPLITK || !bias) ? 0.f : bias[col];
#pragma unroll
      for (int r = 0; r < 4; r++) {
        float v = acc[i][j][r] + bs;
        if (RESID) v += resid[(size_t)(row + r) * N + col];
        if (RELU) v = fmaxf(v, 0.f);
        if (OUT_MODE == 0) ((float*)op)[(size_t)(row + r) * N + col] = v;
        else               ((unsigned short*)op)[(size_t)(row + r) * N + col] = f2bf(v);
      }
    }
}

// ---------------- batched 3-mat GEMM, ring-3 ---------------------------------
__global__ __launch_bounds__(256) void k_gemm_qkv(
    const unsigned short* __restrict__ a0, const unsigned short* __restrict__ a1,
    const unsigned short* __restrict__ a2,
    const unsigned short* __restrict__ Bt,
    const float* __restrict__ b0, const float* __restrict__ b1, const float* __restrict__ b2,
    unsigned short* __restrict__ o0, unsigned short* __restrict__ o1, unsigned short* __restrict__ o2,
    int vmat, float qscale, int M, int K) {
  __shared__ unsigned short Alds[3][128 * 32];
  __shared__ unsigned short Blds[3][128 * 32];
  int tid = threadIdx.x;
  int w = tid >> 6, lane = tid & 63;
  int wr = w >> 1, wc = w & 1;
  int l15 = lane & 15, l4 = lane >> 4;
  int bxs, bys, z;
  xcd_swz(bxs, bys, z);
  const unsigned short* A  = (z == 0) ? a0 : (z == 1) ? a1 : a2;
  const unsigned short* Bz = Bt + (size_t)z * 1048576;
  int brow = bys * 128, bcol = bxs * 128;

  f32x4 acc[4][4];
#pragma unroll
  for (int i = 0; i < 4; i++)
#pragma unroll
    for (int j = 0; j < 4; j++) acc[i][j] = (f32x4){0.f, 0.f, 0.f, 0.f};

#define STAGEQ(bufi, kk) do {                                                  \
    _Pragma("unroll")                                                          \
    for (int c = 0; c < 2; c++) {                                              \
      int elem = (c * 256 + tid) * 8;                                          \
      int row = elem >> 5, col = elem & 31;                                    \
      async16(A + (size_t)(brow + row) * K + (kk) + col, &Alds[bufi][elem]);   \
      async16(Bz + (size_t)(bcol + row) * K + (kk) + col, &Blds[bufi][elem]);  \
    } } while (0)

  int nk = K / 32;
  STAGEQ(0, 0);
  STAGEQ(1, 32);
  WAITV(4);
  BARRIER_SB();

  for (int t = 0; t < nk; t++) {
    int buf = t % 3;
    if (t + 2 < nk) STAGEQ((t + 2) % 3, (t + 2) * 32);
    short8 af[4], bfr[4];
#pragma unroll
    for (int i = 0; i < 4; i++) {
      af[i]  = *(const short8*)&Alds[buf][(wr * 64 + i * 16 + l15) * 32 + l4 * 8];
      bfr[i] = *(const short8*)&Blds[buf][(wc * 64 + i * 16 + l15) * 32 + l4 * 8];
    }
#pragma unroll
    for (int i = 0; i < 4; i++)
#pragma unroll
      for (int j = 0; j < 4; j++)
        acc[i][j] = __builtin_amdgcn_mfma_f32_16x16x32_bf16(af[i], bfr[j], acc[i][j], 0, 0, 0);
    if (t + 2 < nk) WAITV(4);
    else if (t + 1 < nk) WAITV(0);
    if (t + 1 < nk) BARRIER_SB();
  }
#undef STAGEQ

  const float* bias = (z == 0) ? b0 : (z == 1) ? b1 : b2;
  unsigned short* op = (z == 0) ? o0 : (z == 1) ? o1 : o2;
  bool tr = (z == vmat);
#pragma unroll
  for (int i = 0; i < 4; i++)
#pragma unroll
    for (int j = 0; j < 4; j++) {
      int row = brow + wr * 64 + i * 16 + l4 * 4;
      int colL = bcol + wc * 64 + j * 16 + l15;
      float bs = bias[colL];
#pragma unroll
      for (int r = 0; r < 4; r++) {
        float v = acc[i][j][r] + bs;
        if (z == 0) v *= qscale;
        if (tr) op[(size_t)colL * M + row + r] = f2bf(v);
        else    op[(size_t)(row + r) * 1024 + colL] = f2bf(v);
      }
    }
}

// ---------------- flash attention (4-wave, ring-2 K/V in LDS) ----------------
template<bool CAUSAL, int NF>
__global__ __launch_bounds__(256) void k_attn(
    const unsigned short* __restrict__ Q,
    const unsigned short* __restrict__ Kb,
    const unsigned short* __restrict__ Vt,
    const float* __restrict__ pm,     // [B][S] padding mask or null
    unsigned short* __restrict__ out) {
  __shared__ unsigned short Klds[2][64 * 64];
  __shared__ unsigned short Vlds[2][64 * 64];
  __shared__ unsigned short Pw[4][NF][16 * 72];
  int tid = threadIdx.x, w = tid >> 6, lane = tid & 63;
  int l15 = lane & 15, l4 = lane >> 4;
  int h = blockIdx.y, b = blockIdx.z;
  const int NPASS = CAUSAL ? 2 : 1;

#define STAGE(bufi, kt_) do {                                                  \
    _Pragma("unroll")                                                          \
    for (int c = 0; c < 2; c++) {                                              \
      int e0 = w * 1024 + c * 512;                                             \
      int elem = e0 + lane * 8;                                                \
      int row_ = elem >> 6;                                                    \
      int col_ = (elem & 63) ^ ((row_ & 7) << 3);                              \
      async16(Kb + (size_t)(b * SS + (kt_) * 64 + row_) * DM + h * 64 + col_,  \
              &Klds[bufi][elem]);                                              \
      async16(Vt + (size_t)(h * 64 + row_) * MT + b * SS + (kt_) * 64 + col_,  \
              &Vlds[bufi][elem]);                                              \
    } } while (0)

  for (int pass = 0; pass < NPASS; pass++) {
    int qt = CAUSAL ? (pass == 0 ? (31 - (int)blockIdx.x) : (int)blockIdx.x)
                    : (int)blockIdx.x;
    int qbase = qt * (NF * 64) + w * (NF * 16);

    short8 qf[NF][2];
#pragma unroll
    for (int f = 0; f < NF; f++) {
      size_t qrow = (size_t)b * SS + qbase + f * 16 + l15;
#pragma unroll
      for (int ks = 0; ks < 2; ks++)
        qf[f][ks] = *(const short8*)(Q + qrow * DM + h * 64 + ks * 32 + l4 * 8);
    }

    float mrow[NF], lrow[NF];
    f32x4 accO[NF][4];
#pragma unroll
    for (int f = 0; f < NF; f++) {
      mrow[f] = -1e30f; lrow[f] = 0.f;
#pragma unroll
      for (int d = 0; d < 4; d++) accO[f][d] = (f32x4){0.f, 0.f, 0.f, 0.f};
    }

    int ktend = CAUSAL ? qt : (SS / 64 - 1);
    if (pass) BARRIER_SB();              // all waves done with LDS from pass 0
    STAGE(0, 0);
    WAITV(0);
    BARRIER_SB();

    for (int kt = 0; kt <= ktend; kt++) {
      int buf = kt & 1;
      bool more = (kt + 1 <= ktend);
      if (more) STAGE(buf ^ 1, kt + 1);   // early issue; drain at tile end

      {
        f32x4 sa[NF][4];
#pragma unroll
        for (int f = 0; f < NF; f++)
#pragma unroll
          for (int nt = 0; nt < 4; nt++) sa[f][nt] = (f32x4){0.f, 0.f, 0.f, 0.f};
        __builtin_amdgcn_s_setprio(1);
#pragma unroll
        for (int ks = 0; ks < 2; ks++)
#pragma unroll
          for (int nt = 0; nt < 4; nt++) {
            int kr = nt * 16 + l15;
            short8 kf = *(const short8*)&Klds[buf][kr * 64 + ((ks * 32 + l4 * 8) ^ ((kr & 7) << 3))];
#pragma unroll
            for (int f = 0; f < NF; f++)
              sa[f][nt] = __builtin_amdgcn_mfma_f32_16x16x32_bf16(kf, qf[f][ks], sa[f][nt], 0, 0, 0);
          }
        __builtin_amdgcn_s_setprio(0);

        float pmb[16];
        if (!CAUSAL) {
#pragma unroll
          for (int nt = 0; nt < 4; nt++) {
            float4 pmv = *(const float4*)(pm + b * SS + kt * 64 + nt * 16 + l4 * 4);
#pragma unroll
            for (int r = 0; r < 4; r++) pmb[nt * 4 + r] = ((const float*)&pmv)[r] * -1e30f;
          }
        }
        bool diag = CAUSAL && (kt * 64 + 63 > qbase);

        // ---- scores (Q pre-scaled) + per-lane max3 tree
        float sv[NF][16], tm[NF];
#pragma unroll
        for (int f = 0; f < NF; f++) {
          if (CAUSAL && !diag) {
#pragma unroll
            for (int i = 0; i < 16; i++) sv[f][i] = sa[f][i >> 2][i & 3];
          } else if (CAUSAL) {
#pragma unroll
            for (int nt = 0; nt < 4; nt++)
#pragma unroll
              for (int r = 0; r < 4; r++) {
                float s = sa[f][nt][r];
                int kg = kt * 64 + nt * 16 + l4 * 4 + r;
                int qg = qbase + f * 16 + l15;
                if (kg > qg) s = -1e30f;
                sv[f][nt * 4 + r] = s;
              }
          } else {
#pragma unroll
            for (int i = 0; i < 16; i++)
              sv[f][i] = sa[f][i >> 2][i & 3] + pmb[i];
          }
          tm[f] = max16(sv[f]);
        }

        // ---- cross-lane row max: frags overlap in latency
        float sA[NF];
#pragma unroll
        for (int f = 0; f < NF; f++) sA[f] = swz16(tm[f]);
#pragma unroll
        for (int f = 0; f < NF; f++) tm[f] = fmaxf(tm[f], sA[f]);
        float xA[NF];
#pragma unroll
        for (int f = 0; f < NF; f++) xA[f] = __shfl_xor(tm[f], 32);
#pragma unroll
        for (int f = 0; f < NF; f++) tm[f] = fmaxf(tm[f], xA[f]);

#pragma unroll
        for (int f = 0; f < NF; f++) {
          if (!__all(tm[f] - mrow[f] <= 8.f)) {
            float mnew = fmaxf(mrow[f], tm[f]);
            float corr = EXP2(mrow[f] - mnew);
            mrow[f] = mnew;
            lrow[f] *= corr;
#pragma unroll
            for (int r = 0; r < 4; r++) {
              float cq = __shfl(corr, l4 * 4 + r);
#pragma unroll
              for (int dt = 0; dt < 4; dt++) accO[f][dt][r] *= cq;
            }
          }

          float p[16];
#pragma unroll
          for (int i = 0; i < 16; i++) p[i] = EXP2(sv[f][i] - mrow[f]);
          float a8[8];
#pragma unroll
          for (int i = 0; i < 8; i++) a8[i] = p[i] + p[i + 8];
#pragma unroll
          for (int i = 0; i < 4; i++) a8[i] = a8[i] + a8[i + 4];
          lrow[f] += (a8[0] + a8[1]) + (a8[2] + a8[3]);

#pragma unroll
          for (int nt = 0; nt < 4; nt++) {
            uint2 u;
            u.x = cvt_pk_bf16(p[nt * 4 + 0], p[nt * 4 + 1]);
            u.y = cvt_pk_bf16(p[nt * 4 + 2], p[nt * 4 + 3]);
            *(uint2*)&Pw[w][f][l15 * 72 + nt * 16 + l4 * 4] = u;
          }
        }

        __builtin_amdgcn_s_setprio(1);
#pragma unroll
        for (int ks = 0; ks < 2; ks++) {
          short8 pf[NF];
#pragma unroll
          for (int f = 0; f < NF; f++)
            pf[f] = *(const short8*)&Pw[w][f][l15 * 72 + ks * 32 + l4 * 8];
#pragma unroll
          for (int dt = 0; dt < 4; dt++) {
            int vr = dt * 16 + l15;
            short8 vf = *(const short8*)&Vlds[buf][vr * 64 + ((ks * 32 + l4 * 8) ^ ((vr & 7) << 3))];
#pragma unroll
            for (int f = 0; f < NF; f++)
              accO[f][dt] = __builtin_amdgcn_mfma_f32_16x16x32_bf16(pf[f], vf, accO[f][dt], 0, 0, 0);
          }
        }
        __builtin_amdgcn_s_setprio(0);
      }

      if (more) {
        WAITV(0);        // next tile fully in LDS
        BARRIER_SB();
      }
    }

#pragma unroll
    for (int f = 0; f < NF; f++) {
      lrow[f] += swz16(lrow[f]);
      lrow[f] += __shfl_xor(lrow[f], 32);
    }
#pragma unroll
    for (int f = 0; f < NF; f++)
#pragma unroll
      for (int r = 0; r < 4; r++) {
        float lq = __shfl(lrow[f], l4 * 4 + r);
        float inv = 1.f / lq;
        size_t row = (size_t)b * SS + qbase + f * 16 + l4 * 4 + r;
#pragma unroll
        for (int dt = 0; dt < 4; dt++)
          out[row * DM + h * 64 + dt * 16 + l15] = f2bf(accO[f][dt][r] * inv);
      }
  }
#undef STAGE
}

// ---------------- LayerNorm over D=1024, one block per row --------------------
__global__ __launch_bounds__(256) void k_ln(
    const float* __restrict__ in, const float* __restrict__ in2,
    const float* __restrict__ in3, const float* __restrict__ in4,
    const float* __restrict__ resid, const float* __restrict__ bias,
    const float* __restrict__ g, const float* __restrict__ bb,
    float* __restrict__ outf, unsigned short* __restrict__ outb) {
  int row = blockIdx.x, tid = threadIdx.x;
  int w = tid >> 6;
  __shared__ float red[4];
  float4 v = *(const float4*)(in + (size_t)row * 1024 + tid * 4);
  if (in2) {
    float4 v2 = *(const float4*)(in2 + (size_t)row * 1024 + tid * 4);
    v.x += v2.x; v.y += v2.y; v.z += v2.z; v.w += v2.w;
  }
  if (in3) {
    float4 v2 = *(const float4*)(in3 + (size_t)row * 1024 + tid * 4);
    v.x += v2.x; v.y += v2.y; v.z += v2.z; v.w += v2.w;
  }
  if (in4) {
    float4 v2 = *(const float4*)(in4 + (size_t)row * 1024 + tid * 4);
    v.x += v2.x; v.y += v2.y; v.z += v2.z; v.w += v2.w;
  }
  if (resid) {
    float4 v2 = *(const float4*)(resid + (size_t)row * 1024 + tid * 4);
    v.x += v2.x; v.y += v2.y; v.z += v2.z; v.w += v2.w;
  }
  if (bias) {
    float4 v2 = *(const float4*)(bias + tid * 4);
    v.x += v2.x; v.y += v2.y; v.z += v2.z; v.w += v2.w;
  }
  float s = v.x + v.y + v.z + v.w;
#pragma unroll
  for (int d = 1; d < 64; d <<= 1) s += __shfl_xor(s, d);
  if ((tid & 63) == 0) red[w] = s;
  __syncthreads();
  float mu = (red[0] + red[1] + red[2] + red[3]) * (1.f / 1024.f);
  float d0 = v.x - mu, d1 = v.y - mu, d2 = v.z - mu, d3 = v.w - mu;
  float q = d0 * d0 + d1 * d1 + d2 * d2 + d3 * d3;
#pragma unroll
  for (int d = 1; d < 64; d <<= 1) q += __shfl_xor(q, d);
  __syncthreads();
  if ((tid & 63) == 0) red[w] = q;
  __syncthreads();
  float var = (red[0] + red[1] + red[2] + red[3]) * (1.f / 1024.f);
  float rs = rsqrtf(var + 1e-6f);
  float4 gg = *(const float4*)(g + tid * 4);
  float4 bv = *(const float4*)(bb + tid * 4);
  float y0 = d0 * rs * gg.x + bv.x;
  float y1 = d1 * rs * gg.y + bv.y;
  float y2 = d2 * rs * gg.z + bv.z;
  float y3 = d3 * rs * gg.w + bv.w;
  if (outf) {
    float4 o; o.x = y0; o.y = y1; o.z = y2; o.w = y3;
    *(float4*)(outf + (size_t)row * 1024 + tid * 4) = o;
  }
  if (outb) {
    uint2 u;
    u.x = (unsigned)f2bf(y0) | ((unsigned)f2bf(y1) << 16);
    u.y = (unsigned)f2bf(y2) | ((unsigned)f2bf(y3) << 16);
    *(uint2*)(outb + (size_t)row * 1024 + tid * 4) = u;
  }
}

extern "C" void kernel_launch(void* const* d_in, const int* in_sizes, int n_in,
                              void* d_out, int out_size, void* d_ws, size_t ws_size,
                              hipStream_t stream) {
  const float* x    = (const float*)d_in[0];
  const float* enc  = (const float*)d_in[1];
  const float* pm   = (const float*)d_in[3];
  const float* wq1  = (const float*)d_in[4];   const float* bq1 = (const float*)d_in[5];
  const float* wk1  = (const float*)d_in[6];   const float* bk1 = (const float*)d_in[7];
  const float* wv1  = (const float*)d_in[8];   const float* bv1 = (const float*)d_in[9];
  const float* wo1  = (const float*)d_in[10];  const float* bo1 = (const float*)d_in[11];
  const float* wq2  = (const float*)d_in[12];  const float* bq2 = (const float*)d_in[13];
  const float* wk2  = (const float*)d_in[14];  const float* bk2 = (const float*)d_in[15];
  const float* wv2  = (const float*)d_in[16];  const float* bv2 = (const float*)d_in[17];
  const float* wo2  = (const float*)d_in[18];  const float* bo2 = (const float*)d_in[19];
  const float* fw1  = (const float*)d_in[20];  const float* fb1 = (const float*)d_in[21];
  const float* fw2  = (const float*)d_in[22];  const float* fb2 = (const float*)d_in[23];
  const float* ln1g = (const float*)d_in[24];  const float* ln1b = (const float*)d_in[25];
  const float* ln2g = (const float*)d_in[26];  const float* ln2b = (const float*)d_in[27];
  const float* ln3g = (const float*)d_in[28];  const float* ln3b = (const float*)d_in[29];

  char* ws = (char*)d_ws;
  unsigned short* XB = (unsigned short*)(ws + 0);          // 8.39 MB
  unsigned short* EB = (unsigned short*)(ws + 8388608);
  unsigned short* Qb = (unsigned short*)(ws + 16777216);
  unsigned short* Kb = (unsigned short*)(ws + 25165824);
  unsigned short* Vt = (unsigned short*)(ws + 33554432);   // [DM][MT]
  unsigned short* AT = (unsigned short*)(ws + 41943040);
  float*          T  = (float*)(ws + 50331648);            // 16.78 MB
  float*          R  = (float*)(ws + 67108864);            // 16.78 MB
  unsigned short* RB = (unsigned short*)(ws + 83886080);
  unsigned short* WT0 = (unsigned short*)(ws + 92274688);  // 8 x 2 MB
  unsigned short* W1T = (unsigned short*)(ws + 92274688 + 16777216);  // 8.39 MB
  unsigned short* W2T = (unsigned short*)(ws + 92274688 + 25165824);  // 8.39 MB
  unsigned short* H   = (unsigned short*)(ws + 0);         // overlaps XB..Kb (dead then)
  float*          T1o = (float*)(ws + 16777216);           // overlaps Qb+Kb (dead at O-proj)
  // FFN2 4-way split-K partials (regions dead at FFN2 time):
  float*          P0  = T;
  float*          P1  = (float*)(ws + 33554432);
  float*          P2  = (float*)(ws + 83886080);
  float*          P3  = (float*)(ws + 100663296);

  // ---- conversions ----
  k_conv2<<<8192, 256, 0, stream>>>(x, enc, XB, EB);
  PtrArr ptrs;
  ptrs.p[0] = wq1; ptrs.p[1] = wk1; ptrs.p[2] = wv1; ptrs.p[3] = wo1;
  ptrs.p[4] = wq2; ptrs.p[5] = wk2; ptrs.p[6] = wv2; ptrs.p[7] = wo2;
  k_transpose8<<<dim3(16, 16, 8), 256, 0, stream>>>(ptrs, WT0);
  k_transpose_bf16<<<dim3(64, 16), 256, 0, stream>>>(fw1, W1T, 1024, 4096);
  k_transpose_bf16<<<dim3(16, 64), 256, 0, stream>>>(fw2, W2T, 4096, 1024);

  hipError_t e1 = hipFuncSetAttribute(
      reinterpret_cast<const void*>(k_gemm256<1, true>),
      hipFuncAttributeMaxDynamicSharedMemorySize, 131072);
  hipError_t e2 = hipFuncSetAttribute(
      reinterpret_cast<const void*>(k_gemm256<0, false>),
      hipFuncAttributeMaxDynamicSharedMemorySize, 131072);
  bool big = (e1 == hipSuccess && e2 == hipSuccess);

  // ---- self attention ----
  k_gemm_qkv<<<dim3(8, 32, 3), 256, 0, stream>>>(XB, XB, XB, WT0, bq1, bk1, bv1,
                                                 Qb, Kb, Vt, 2, QSCALE, MT, DM);
  k_attn<true, 1><<<dim3(16, 16, 2), 256, 0, stream>>>(Qb, Kb, Vt, nullptr, AT);
  k_gemm<64, 0, false, false, true><<<dim3(8, 64, 2), 256, 0, stream>>>(
      AT, WT0 + 3 * 1048576, nullptr, nullptr, T, T1o, MT, DM, DM, 512);
  k_ln<<<4096, 256, 0, stream>>>(T, T1o, nullptr, nullptr, x, bo1, ln1g, ln1b, R, RB);

  // ---- cross attention ----
  k_gemm_qkv<<<dim3(8, 32, 3), 256, 0, stream>>>(RB, EB, EB, WT0 + 4 * 1048576,
                                                 bq2, bk2, bv2, Qb, Kb, Vt, 2, QSCALE, MT, DM);
  k_attn<false, 2><<<dim3(16, 16, 2), 256, 0, stream>>>(Qb, Kb, Vt, pm, AT);
  k_gemm<64, 0, false, false, true><<<dim3(8, 64, 2), 256, 0, stream>>>(
      AT, WT0 + 7 * 1048576, nullptr, nullptr, T, T1o, MT, DM, DM, 512);
  k_ln<<<4096, 256, 0, stream>>>(T, T1o, nullptr, nullptr, R, bo2, ln2g, ln2b, R, RB);

  // ---- FFN ----
  if (big) {
    k_gemm256<1, true><<<dim3(16, 16, 1), 512, 131072, stream>>>(
        RB, W1T, fb1, H, nullptr, nullptr, nullptr, MT, 4096, DM, DM);
    k_gemm256<0, false><<<dim3(4, 16, 4), 512, 131072, stream>>>(
        H, W2T, nullptr, P0, P1, P2, P3, MT, DM, 4096, 1024);
    k_ln<<<4096, 256, 0, stream>>>(P0, P1, P2, P3, R, fb2, ln3g, ln3b,
                                   (float*)d_out, nullptr);
  } else {
    k_gemm<128, 1, true, false, false><<<dim3(32, 32), 256, 0, stream>>>(
        RB, W1T, fb1, nullptr, H, nullptr, MT, 4096, DM, 1024);
    k_gemm<64, 0, false, false, true><<<dim3(8, 64, 2), 256, 0, stream>>>(
        H, W2T, nullptr, nullptr, T, (float*)(ws + 33554432), MT, DM, 4096, 2048);
    k_ln<<<4096, 256, 0, stream>>>(T, (float*)(ws + 33554432), nullptr, nullptr,
                                   R, fb2, ln3g, ln3b, (float*)d_out, nullptr);
  }
}